// Round 1
// baseline (204.820 us; speedup 1.0000x reference)
//
#include <hip/hip_runtime.h>

typedef _Float16 half_t;
typedef __attribute__((ext_vector_type(8))) _Float16 half8;   // MFMA A/B frag (4 VGPRs)
typedef __attribute__((ext_vector_type(4))) float f32x4;      // MFMA C/D frag

#define NPOLY 16384   // B*N
#define PPTS  32
#define CIN   9

// ---- workspace layout (units of half_t) ----
// 52 B-frags of 512 halfs each: enc pre 0..3, m1 4..19, m2 20..27,
// out1 28..35, out2 36..51. Then 192 floats of folded BN bias.
#define ENC_OFF   0
#define W1_OFF    (28 * 512)
#define W2_OFF    (36 * 512)
#define NFRAG     52
#define BIAS_HOFF (52 * 512)   // float area starts here (16B aligned)

__device__ __forceinline__ half8 ld8(const half_t* p){
    return *reinterpret_cast<const half8*>(p);
}
__device__ __forceinline__ f32x4 MFMA(half8 a, half8 b, f32x4 c){
    return __builtin_amdgcn_mfma_f32_16x16x32_f16(a, b, c, 0, 0, 0);
}
// Fragment layouts (measured, learn_hip m89/m120; dtype-independent):
//   A[m][k]: m = lane&15 (+16*mt), k = (lane>>4)*8 + j (+32*ks)
//   B[k][n]: n = lane&15 (+16*nt), k = (lane>>4)*8 + j (+32*ks)
//   C/D[row][col]: col = lane&15 (+16*nt), row = (lane>>4)*4 + r (+16*mt)

// =====================================================================
// Prep kernel: fold BN scale into weights, convert fp32 -> f16 MFMA
// B-frag layout in workspace. Runs once per graph iteration (~2us);
// removes the identical per-block staging VALU work from 1024 blocks.
// =====================================================================
__global__ __launch_bounds__(64) void k_prep(
    const float* __restrict__ w_pre, const float* __restrict__ b_pre,
    const float* __restrict__ g_pre, const float* __restrict__ be_pre,
    const float* __restrict__ rm_pre, const float* __restrict__ rv_pre,
    const float* __restrict__ w_m1, const float* __restrict__ b_m1,
    const float* __restrict__ g_m1, const float* __restrict__ be_m1,
    const float* __restrict__ rm_m1, const float* __restrict__ rv_m1,
    const float* __restrict__ w_m2, const float* __restrict__ b_m2,
    const float* __restrict__ g_m2, const float* __restrict__ be_m2,
    const float* __restrict__ rm_m2, const float* __restrict__ rv_m2,
    const float* __restrict__ w1, const float* __restrict__ w2,
    half_t* __restrict__ wsH)
{
    const int b = blockIdx.x, tid = threadIdx.x;
    const int l15 = tid & 15, q = tid >> 4;
    if (b < NFRAG) {
        half8 v;
        if (b < 28) {
            // encoder frags: BN scale folded (sA)
            const float *W, *G, *RV; int K, ks, nt;
            if (b < 4)       { W = w_pre; G = g_pre; RV = rv_pre; K = CIN; ks = 0; nt = b; }
            else if (b < 20) { W = w_m1;  G = g_m1;  RV = rv_m1;  K = 128; int f = b - 4;  ks = f >> 2; nt = f & 3; }
            else             { W = w_m2;  G = g_m2;  RV = rv_m2;  K = 64;  int f = b - 20; ks = f >> 2; nt = f & 3; }
            int col = nt * 16 + l15;
            int kb  = ks * 32 + q * 8;
            float sA = G[col] * rsqrtf(RV[col] + 1e-5f);
            #pragma unroll
            for (int j = 0; j < 8; j++) {
                int k  = kb + j;
                int ka = (k < K) ? k : 0;
                float w = W[ka * 64 + col] * sA;
                v[j] = (k < K) ? (half_t)w : (half_t)0.f;
            }
        } else if (b < 36) {
            // out1 frags (64x64), no BN
            int f = b - 28, ks = f >> 2, nt = f & 3;
            int col = nt * 16 + l15, row = ks * 32 + q * 8;
            #pragma unroll
            for (int j = 0; j < 8; j++) v[j] = (half_t)w1[(row + j) * 64 + col];
        } else {
            // out2 frags (64x128), no BN
            int f = b - 36, ks = f >> 3, nt = f & 7;
            int col = nt * 16 + l15, row = ks * 32 + q * 8;
            #pragma unroll
            for (int j = 0; j < 8; j++) v[j] = (half_t)w2[(row + j) * 128 + col];
        }
        *reinterpret_cast<half8*>(wsH + b * 512 + tid * 8) = v;
    } else {
        // folded BN bias vectors: sC = (b - rm)*g*rsqrt(rv+eps) + beta
        float* bf = reinterpret_cast<float*>(wsH + BIAS_HOFF);
        int h = tid;
        if (h < 64) {
            bf[h]       = (b_pre[h] - rm_pre[h]) * g_pre[h] * rsqrtf(rv_pre[h] + 1e-5f) + be_pre[h];
            bf[64 + h]  = (b_m1[h]  - rm_m1[h])  * g_m1[h]  * rsqrtf(rv_m1[h]  + 1e-5f) + be_m1[h];
            bf[128 + h] = (b_m2[h]  - rm_m2[h])  * g_m2[h]  * rsqrtf(rv_m2[h]  + 1e-5f) + be_m2[h];
        }
    }
}

// =====================================================================
// Fully fused: pre-MLP -> mask -> maxpool -> concat -> l1 -> l2 ->
// masked max -> out1(relu) -> out2 -> valid mask.
// Block = 256 threads (4 waves) = 16 polylines; wave w owns rows 4w..4w+3.
// Weights come pre-folded/pre-converted from the workspace (prep kernel)
// as B-frags read straight from global: the 28KB encoder set is
// L1-resident, so no lds_w -> LDS 24.6 KB -> 6 blocks/CU capacity
// (grid 1024 -> 4 resident blocks/CU = 16 waves/CU, was 12).
// =====================================================================
__global__ __launch_bounds__(256, 4) void k_fused(
    const float* __restrict__ px,        // [NPOLY][32][9]
    const int*   __restrict__ pmask,     // [NPOLY][32]
    const float* __restrict__ b1, const float* __restrict__ b2,
    const half_t* __restrict__ wsH,
    float* __restrict__ out)
{
    __shared__ __align__(16) half_t fg[4][32 * 72];    // 18 KB per-wave f/g A-tiles
    __shared__ __align__(16) half_t pooledb[4][64];    // 0.5 KB
    __shared__ __align__(16) half_t ft[16 * 72];       // 2.25 KB feat A-tile (16 rows)
    __shared__ __align__(16) half_t qt[16 * 72];       // 2.25 KB out1 A-tile
    __shared__ int maskb[4][2][32];                    // 1 KB (double-buffered)
    __shared__ int validb[16];

    const int tid  = threadIdx.x;
    const int wave = tid >> 6, lane = tid & 63, l15 = lane & 15, q = lane >> 4;

    // ---- per-lane BN bias consts (MFMA acc init), h = nt*16+l15 ----
    const float* bf = reinterpret_cast<const float*>(wsH + BIAS_HOFF);
    float sC0[4], sC1[4], sC2[4];
    #pragma unroll
    for (int nt = 0; nt < 4; nt++) {
        int h = nt * 16 + l15;
        sC0[nt] = bf[h];
        sC1[nt] = bf[64 + h];
        sC2[nt] = bf[128 + h];
    }

    const int nbase = blockIdx.x * 16 + wave * 4;

    // ---- prefetch iter 0 x (lanes q<2) and mask (lanes 32..63) ----
    float xr[2][8];
    #pragma unroll
    for (int mt = 0; mt < 2; mt++) {
        const float* src = px + ((long)nbase * PPTS + l15 + 16 * mt) * CIN;
        if (q == 0) {
            #pragma unroll
            for (int j = 0; j < 8; j++) xr[mt][j] = src[j];
        } else if (q == 1) {
            xr[mt][0] = src[8];
        }
    }
    if (lane >= 32) maskb[wave][0][lane - 32] = pmask[nbase * PPTS + (lane - 32)];

    __syncthreads();   // maskb visible

    #pragma unroll
    for (int it = 0; it < 4; ++it) {
        const int n = nbase + it;

        // ---- issue next-iteration prefetch loads (consumed at iter end) ----
        float xn[2][8]; int mnext = 0;
        if (it < 3) {
            #pragma unroll
            for (int mt = 0; mt < 2; mt++) {
                const float* src = px + ((long)(n + 1) * PPTS + l15 + 16 * mt) * CIN;
                if (q == 0) {
                    #pragma unroll
                    for (int j = 0; j < 8; j++) xn[mt][j] = src[j];
                } else if (q == 1) {
                    xn[mt][0] = src[8];
                }
            }
            if (lane >= 32) mnext = pmask[(n + 1) * PPTS + (lane - 32)];
        }

        // ---- build x A-frags (K=9 zero-padded to 32) ----
        half8 xa[2];
        #pragma unroll
        for (int mt = 0; mt < 2; mt++) {
            half8 v;
            #pragma unroll
            for (int j = 0; j < 8; j++) v[j] = (half_t)0.f;
            if (q == 0) {
                #pragma unroll
                for (int j = 0; j < 8; j++) v[j] = (half_t)xr[mt][j];
            } else if (q == 1) {
                v[0] = (half_t)xr[mt][0];
            }
            xa[mt] = v;
        }

        // ---- pre layer: acc init = sC0 (BN bias) ----
        f32x4 acc[2][4];
        #pragma unroll
        for (int mt = 0; mt < 2; mt++)
            #pragma unroll
            for (int nt = 0; nt < 4; nt++)
                #pragma unroll
                for (int r = 0; r < 4; r++) acc[mt][nt][r] = sC0[nt];

        #pragma unroll
        for (int nt = 0; nt < 4; nt++) {
            half8 b = ld8(&wsH[(ENC_OFF + nt) * 512 + lane * 8]);
            acc[0][nt] = MFMA(xa[0], b, acc[0][nt]);
            acc[1][nt] = MFMA(xa[1], b, acc[1][nt]);
        }

        float maskf[8];
        #pragma unroll
        for (int mt = 0; mt < 2; mt++)
            #pragma unroll
            for (int r = 0; r < 4; r++)
                maskf[mt * 4 + r] = maskb[wave][it & 1][mt * 16 + q * 4 + r] ? 1.f : 0.f;

        // ReLU+mask, write masked f into A-tile, track pooled max (vals >= 0)
        float pm[4];
        #pragma unroll
        for (int nt = 0; nt < 4; nt++) {
            float m = 0.f;
            #pragma unroll
            for (int mt = 0; mt < 2; mt++)
                #pragma unroll
                for (int r = 0; r < 4; r++) {
                    float v = fmaxf(acc[mt][nt][r], 0.f) * maskf[mt * 4 + r];
                    fg[wave][(mt * 16 + q * 4 + r) * 72 + nt * 16 + l15] = (half_t)v;
                    m = fmaxf(m, v);
                }
            m = fmaxf(m, __shfl_xor(m, 16));
            m = fmaxf(m, __shfl_xor(m, 32));
            pm[nt] = m;
        }
        {
            float pv = (q == 0) ? pm[0] : (q == 1) ? pm[1] : (q == 2) ? pm[2] : pm[3];
            pooledb[wave][lane] = (half_t)pv;   // col = q*16+l15 = lane
        }

        // ---- l1: A = [f | pooled-bcast] (32x128) @ (128x64), acc init sC1 ----
        f32x4 acc1[2][4];
        #pragma unroll
        for (int mt = 0; mt < 2; mt++)
            #pragma unroll
            for (int nt = 0; nt < 4; nt++)
                #pragma unroll
                for (int r = 0; r < 4; r++) acc1[mt][nt][r] = sC1[nt];

        half8 pa0 = ld8(&pooledb[wave][q * 8]);
        half8 pa1 = ld8(&pooledb[wave][32 + q * 8]);
        #pragma unroll
        for (int ks = 0; ks < 2; ks++) {
            half8 a0 = ld8(&fg[wave][l15 * 72 + ks * 32 + q * 8]);
            half8 a1 = ld8(&fg[wave][(l15 + 16) * 72 + ks * 32 + q * 8]);
            #pragma unroll
            for (int nt = 0; nt < 4; nt++) {
                half8 b = ld8(&wsH[(4 + ks * 4 + nt) * 512 + lane * 8]);
                acc1[0][nt] = MFMA(a0, b, acc1[0][nt]);
                acc1[1][nt] = MFMA(a1, b, acc1[1][nt]);
            }
        }
        #pragma unroll
        for (int ks = 2; ks < 4; ks++) {
            half8 ap = (ks == 2) ? pa0 : pa1;
            #pragma unroll
            for (int nt = 0; nt < 4; nt++) {
                half8 b = ld8(&wsH[(4 + ks * 4 + nt) * 512 + lane * 8]);
                acc1[0][nt] = MFMA(ap, b, acc1[0][nt]);
                acc1[1][nt] = MFMA(ap, b, acc1[1][nt]);
            }
        }
        // ReLU only (mask not needed between l1/l2), overwrite fg
        #pragma unroll
        for (int nt = 0; nt < 4; nt++)
            #pragma unroll
            for (int mt = 0; mt < 2; mt++)
                #pragma unroll
                for (int r = 0; r < 4; r++) {
                    float v = fmaxf(acc1[mt][nt][r], 0.f);
                    fg[wave][(mt * 16 + q * 4 + r) * 72 + nt * 16 + l15] = (half_t)v;
                }

        // ---- l2: (32x64) @ (64x64), acc init sC2 ----
        f32x4 acc2[2][4];
        #pragma unroll
        for (int mt = 0; mt < 2; mt++)
            #pragma unroll
            for (int nt = 0; nt < 4; nt++)
                #pragma unroll
                for (int r = 0; r < 4; r++) acc2[mt][nt][r] = sC2[nt];
        #pragma unroll
        for (int ks = 0; ks < 2; ks++) {
            half8 a0 = ld8(&fg[wave][l15 * 72 + ks * 32 + q * 8]);
            half8 a1 = ld8(&fg[wave][(l15 + 16) * 72 + ks * 32 + q * 8]);
            #pragma unroll
            for (int nt = 0; nt < 4; nt++) {
                half8 b = ld8(&wsH[(20 + ks * 4 + nt) * 512 + lane * 8]);
                acc2[0][nt] = MFMA(a0, b, acc2[0][nt]);
                acc2[1][nt] = MFMA(a1, b, acc2[1][nt]);
            }
        }

        // ReLU+mask, masked max over points -> feat row into ft tile (f16)
        float fm[4];
        #pragma unroll
        for (int nt = 0; nt < 4; nt++) {
            float m = 0.f;
            #pragma unroll
            for (int mt = 0; mt < 2; mt++)
                #pragma unroll
                for (int r = 0; r < 4; r++) {
                    float v = fmaxf(acc2[mt][nt][r], 0.f) * maskf[mt * 4 + r];
                    m = fmaxf(m, v);
                }
            m = fmaxf(m, __shfl_xor(m, 16));
            m = fmaxf(m, __shfl_xor(m, 32));
            fm[nt] = m;
        }
        float fv = (q == 0) ? fm[0] : (q == 1) ? fm[1] : (q == 2) ? fm[2] : fm[3];
        ft[(wave * 4 + it) * 72 + lane] = (half_t)fv;   // row = 4w+it, col = lane

        int lm = 0;
        #pragma unroll
        for (int j = 0; j < 8; j++) lm |= (maskf[j] != 0.f);
        unsigned long long bal = __ballot(lm);
        if (lane == 0) validb[wave * 4 + it] = bal ? 1 : 0;

        // ---- commit prefetch for next iteration ----
        if (it < 3) {
            if (lane >= 32) maskb[wave][(it + 1) & 1][lane - 32] = mnext;
            #pragma unroll
            for (int mt = 0; mt < 2; mt++)
                #pragma unroll
                for (int j = 0; j < 8; j++) xr[mt][j] = xn[mt][j];
        }
    }

    // =============== out-MLP stage (M=16 rows per block) ===============
    // B-frags pre-converted in workspace; issue loads before the barrier
    // so latency overlaps wave arrival.
    float bb1 = b1[wave * 16 + l15];
    half8 bw1[2];
    #pragma unroll
    for (int ks = 0; ks < 2; ks++)
        bw1[ks] = ld8(&wsH[W1_OFF + (ks * 4 + wave) * 512 + lane * 8]);

    float bb2[2];
    half8 bw2[2][2];   // [ks][nn]
    #pragma unroll
    for (int nn = 0; nn < 2; nn++) {
        bb2[nn] = b2[(wave * 2 + nn) * 16 + l15];
        #pragma unroll
        for (int ks = 0; ks < 2; ks++)
            bw2[ks][nn] = ld8(&wsH[W2_OFF + (ks * 8 + wave * 2 + nn) * 512 + lane * 8]);
    }

    __syncthreads();   // ft + validb complete

    // out1: wave w computes cols w*16..w*16+15
    f32x4 o1;
    #pragma unroll
    for (int r = 0; r < 4; r++) o1[r] = bb1;
    #pragma unroll
    for (int ks = 0; ks < 2; ks++) {
        half8 a = ld8(&ft[l15 * 72 + ks * 32 + q * 8]);
        o1 = MFMA(a, bw1[ks], o1);
    }
    #pragma unroll
    for (int r = 0; r < 4; r++) {
        float v = fmaxf(o1[r], 0.f);
        qt[(q * 4 + r) * 72 + wave * 16 + l15] = (half_t)v;
    }

    __syncthreads();   // qt complete

    // out2: wave w computes cols (2w)*16 .. (2w+1)*16+15
    f32x4 o2[2];
    #pragma unroll
    for (int nn = 0; nn < 2; nn++)
        #pragma unroll
        for (int r = 0; r < 4; r++) o2[nn][r] = bb2[nn];
    #pragma unroll
    for (int ks = 0; ks < 2; ks++) {
        half8 a = ld8(&qt[l15 * 72 + ks * 32 + q * 8]);
        o2[0] = MFMA(a, bw2[ks][0], o2[0]);
        o2[1] = MFMA(a, bw2[ks][1], o2[1]);
    }
    #pragma unroll
    for (int r = 0; r < 4; r++) {
        float vr = validb[q * 4 + r] ? 1.f : 0.f;
        long rowg = (long)(blockIdx.x * 16 + q * 4 + r);
        out[rowg * 128 + (wave * 2 + 0) * 16 + l15] = o2[0][r] * vr;
        out[rowg * 128 + (wave * 2 + 1) * 16 + l15] = o2[1][r] * vr;
    }
}

extern "C" void kernel_launch(void* const* d_in, const int* in_sizes, int n_in,
                              void* d_out, int out_size, void* d_ws, size_t ws_size,
                              hipStream_t stream) {
    (void)in_sizes; (void)n_in; (void)out_size; (void)ws_size;
    half_t* wsH = (half_t*)d_ws;
    k_prep<<<dim3(NFRAG + 1), dim3(64), 0, stream>>>(
        (const float*)d_in[2],  (const float*)d_in[3],  (const float*)d_in[4],
        (const float*)d_in[5],  (const float*)d_in[6],  (const float*)d_in[7],
        (const float*)d_in[8],  (const float*)d_in[9],  (const float*)d_in[10],
        (const float*)d_in[11], (const float*)d_in[12], (const float*)d_in[13],
        (const float*)d_in[14], (const float*)d_in[15], (const float*)d_in[16],
        (const float*)d_in[17], (const float*)d_in[18], (const float*)d_in[19],
        (const float*)d_in[20], (const float*)d_in[22],
        wsH);
    k_fused<<<dim3(NPOLY / 16), dim3(256), 0, stream>>>(
        (const float*)d_in[0], (const int*)d_in[1],
        (const float*)d_in[21], (const float*)d_in[23],
        (const half_t*)wsH,
        (float*)d_out);
}

// Round 2
// 175.753 us; speedup vs baseline: 1.1654x; 1.1654x over previous
//
#include <hip/hip_runtime.h>

typedef _Float16 half_t;
typedef __attribute__((ext_vector_type(8))) _Float16 half8;   // MFMA A/B frag (4 VGPRs)
typedef __attribute__((ext_vector_type(4))) float f32x4;      // MFMA C/D frag

#define NPOLY 16384   // B*N
#define PPTS  32
#define CIN   9

__device__ __forceinline__ half8 ld8(const half_t* p){
    return *reinterpret_cast<const half8*>(p);
}
__device__ __forceinline__ f32x4 MFMA(half8 a, half8 b, f32x4 c){
    return __builtin_amdgcn_mfma_f32_16x16x32_f16(a, b, c, 0, 0, 0);
}
// Fragment layouts (measured, learn_hip m89/m120; dtype-independent):
//   A[m][k]: m = lane&15 (+16*mt), k = (lane>>4)*8 + j (+32*ks)
//   B[k][n]: n = lane&15 (+16*nt), k = (lane>>4)*8 + j (+32*ks)
//   C/D[row][col]: col = lane&15 (+16*nt), row = (lane>>4)*4 + r (+16*mt)

// =====================================================================
// Fully fused: pre-MLP -> mask -> maxpool -> concat -> l1 -> l2 ->
// masked max -> out1(relu) -> out2 -> valid mask.
// NOTE: d_ws is re-poisoned (268 MB fill) every iteration by the harness;
// reading it costs ~100us of L3 drain (measured round 1). All weight
// staging therefore stays IN-KERNEL, amortized per block.
// Block = 512 threads (8 waves) = 32 polylines; wave w owns rows 4w..4w+3.
// Grid = 512 = 2 blocks/CU exactly -> 16 waves/CU resident, single
// perfectly-balanced round (was: 1024 blocks / 3 per CU, ragged).
// LDS 76.1 KB -> 2 blocks/CU.
// =====================================================================
__global__ __launch_bounds__(512, 4) void k_fused(
    const float* __restrict__ px,        // [NPOLY][32][9]
    const int*   __restrict__ pmask,     // [NPOLY][32]
    const float* __restrict__ w_pre, const float* __restrict__ b_pre,
    const float* __restrict__ g_pre, const float* __restrict__ be_pre,
    const float* __restrict__ rm_pre, const float* __restrict__ rv_pre,
    const float* __restrict__ w_m1, const float* __restrict__ b_m1,
    const float* __restrict__ g_m1, const float* __restrict__ be_m1,
    const float* __restrict__ rm_m1, const float* __restrict__ rv_m1,
    const float* __restrict__ w_m2, const float* __restrict__ b_m2,
    const float* __restrict__ g_m2, const float* __restrict__ be_m2,
    const float* __restrict__ rm_m2, const float* __restrict__ rv_m2,
    const float* __restrict__ w1, const float* __restrict__ b1,
    const float* __restrict__ w2, const float* __restrict__ b2,
    float* __restrict__ out)
{
    // encoder weight frags (f16, BN-scaled): pre 0..3, m1 4..19, m2 20..27
    __shared__ __align__(16) half_t lds_w[28 * 512];   // 28 KB
    __shared__ __align__(16) half_t fg[8][32 * 72];    // 36 KB per-wave f/g A-tiles
    __shared__ __align__(16) half_t pooledb[8][64];    // 1 KB
    __shared__ __align__(16) half_t ft[32 * 72];       // 4.5 KB feat A-tile (32 rows)
    __shared__ __align__(16) half_t qt[32 * 72];       // 4.5 KB out1 A-tile
    __shared__ int maskb[8][2][32];                    // 2 KB (double-buffered)
    __shared__ int validb[32];

    const int tid  = threadIdx.x;
    const int wave = tid >> 6, lane = tid & 63, l15 = lane & 15, q = lane >> 4;

    // ---- stage encoder weights, fp32 -> f16, folding BN scale sA ----
    for (int s = tid; s < 28 * 64; s += 512) {
        int frag = s >> 6, ln = s & 63;
        const float *W, *G, *RV; int K, ks, nt;
        if (frag < 4)       { W = w_pre; G = g_pre; RV = rv_pre; K = CIN; ks = 0; nt = frag; }
        else if (frag < 20) { W = w_m1;  G = g_m1;  RV = rv_m1;  K = 128; int f = frag - 4;  ks = f >> 2; nt = f & 3; }
        else                { W = w_m2;  G = g_m2;  RV = rv_m2;  K = 64;  int f = frag - 20; ks = f >> 2; nt = f & 3; }
        int col = nt * 16 + (ln & 15);
        int kb  = ks * 32 + ((ln >> 4) << 3);
        float sA = G[col] * rsqrtf(RV[col] + 1e-5f);
        half_t* dst = &lds_w[s * 8];
        #pragma unroll
        for (int j = 0; j < 8; j++) {
            int k  = kb + j;
            int ka = (k < K) ? k : 0;
            float v = W[ka * 64 + col] * sA;
            dst[j] = (k < K) ? (half_t)v : (half_t)0.f;
        }
    }

    // ---- per-lane BN bias consts (go into MFMA acc init), h = nt*16+l15 ----
    float sC0[4], sC1[4], sC2[4];
    #pragma unroll
    for (int nt = 0; nt < 4; nt++) {
        int h = nt * 16 + l15; float a;
        a = g_pre[h] * rsqrtf(rv_pre[h] + 1e-5f); sC0[nt] = (b_pre[h] - rm_pre[h]) * a + be_pre[h];
        a = g_m1[h]  * rsqrtf(rv_m1[h]  + 1e-5f); sC1[nt] = (b_m1[h]  - rm_m1[h])  * a + be_m1[h];
        a = g_m2[h]  * rsqrtf(rv_m2[h]  + 1e-5f); sC2[nt] = (b_m2[h]  - rm_m2[h])  * a + be_m2[h];
    }

    const int nbase = blockIdx.x * 32 + wave * 4;

    // ---- prefetch iter 0 x (lanes q<2) and mask (lanes 32..63) ----
    float xr[2][8];
    #pragma unroll
    for (int mt = 0; mt < 2; mt++) {
        const float* src = px + ((long)nbase * PPTS + l15 + 16 * mt) * CIN;
        if (q == 0) {
            #pragma unroll
            for (int j = 0; j < 8; j++) xr[mt][j] = src[j];
        } else if (q == 1) {
            xr[mt][0] = src[8];
        }
    }
    if (lane >= 32) maskb[wave][0][lane - 32] = pmask[nbase * PPTS + (lane - 32)];

    __syncthreads();   // weights staged

    // pre-layer B-frags are reused every iteration: hoist to registers
    half8 preb[4];
    #pragma unroll
    for (int nt = 0; nt < 4; nt++) preb[nt] = ld8(&lds_w[nt * 512 + lane * 8]);

    #pragma unroll
    for (int it = 0; it < 4; ++it) {
        const int n = nbase + it;

        // ---- issue next-iteration prefetch loads (consumed at iter end) ----
        float xn[2][8]; int mnext = 0;
        if (it < 3) {
            #pragma unroll
            for (int mt = 0; mt < 2; mt++) {
                const float* src = px + ((long)(n + 1) * PPTS + l15 + 16 * mt) * CIN;
                if (q == 0) {
                    #pragma unroll
                    for (int j = 0; j < 8; j++) xn[mt][j] = src[j];
                } else if (q == 1) {
                    xn[mt][0] = src[8];
                }
            }
            if (lane >= 32) mnext = pmask[(n + 1) * PPTS + (lane - 32)];
        }

        // ---- build x A-frags (K=9 zero-padded to 32) ----
        half8 xa[2];
        #pragma unroll
        for (int mt = 0; mt < 2; mt++) {
            half8 v;
            #pragma unroll
            for (int j = 0; j < 8; j++) v[j] = (half_t)0.f;
            if (q == 0) {
                #pragma unroll
                for (int j = 0; j < 8; j++) v[j] = (half_t)xr[mt][j];
            } else if (q == 1) {
                v[0] = (half_t)xr[mt][0];
            }
            xa[mt] = v;
        }

        // ---- pre layer: acc init = sC0 (BN bias) ----
        f32x4 acc[2][4];
        #pragma unroll
        for (int mt = 0; mt < 2; mt++)
            #pragma unroll
            for (int nt = 0; nt < 4; nt++)
                #pragma unroll
                for (int r = 0; r < 4; r++) acc[mt][nt][r] = sC0[nt];

        #pragma unroll
        for (int nt = 0; nt < 4; nt++) {
            acc[0][nt] = MFMA(xa[0], preb[nt], acc[0][nt]);
            acc[1][nt] = MFMA(xa[1], preb[nt], acc[1][nt]);
        }

        float maskf[8];
        #pragma unroll
        for (int mt = 0; mt < 2; mt++)
            #pragma unroll
            for (int r = 0; r < 4; r++)
                maskf[mt * 4 + r] = maskb[wave][it & 1][mt * 16 + q * 4 + r] ? 1.f : 0.f;

        // ReLU+mask, write masked f into A-tile, track pooled max (vals >= 0)
        float pm[4];
        #pragma unroll
        for (int nt = 0; nt < 4; nt++) {
            float m = 0.f;
            #pragma unroll
            for (int mt = 0; mt < 2; mt++)
                #pragma unroll
                for (int r = 0; r < 4; r++) {
                    float v = fmaxf(acc[mt][nt][r], 0.f) * maskf[mt * 4 + r];
                    fg[wave][(mt * 16 + q * 4 + r) * 72 + nt * 16 + l15] = (half_t)v;
                    m = fmaxf(m, v);
                }
            m = fmaxf(m, __shfl_xor(m, 16));
            m = fmaxf(m, __shfl_xor(m, 32));
            pm[nt] = m;
        }
        {
            float pv = (q == 0) ? pm[0] : (q == 1) ? pm[1] : (q == 2) ? pm[2] : pm[3];
            pooledb[wave][lane] = (half_t)pv;   // col = q*16+l15 = lane
        }

        // ---- l1: A = [f | pooled-bcast] (32x128) @ (128x64), acc init sC1 ----
        f32x4 acc1[2][4];
        #pragma unroll
        for (int mt = 0; mt < 2; mt++)
            #pragma unroll
            for (int nt = 0; nt < 4; nt++)
                #pragma unroll
                for (int r = 0; r < 4; r++) acc1[mt][nt][r] = sC1[nt];

        half8 pa0 = ld8(&pooledb[wave][q * 8]);
        half8 pa1 = ld8(&pooledb[wave][32 + q * 8]);
        #pragma unroll
        for (int ks = 0; ks < 2; ks++) {
            half8 a0 = ld8(&fg[wave][l15 * 72 + ks * 32 + q * 8]);
            half8 a1 = ld8(&fg[wave][(l15 + 16) * 72 + ks * 32 + q * 8]);
            #pragma unroll
            for (int nt = 0; nt < 4; nt++) {
                half8 b = ld8(&lds_w[(4 + ks * 4 + nt) * 512 + lane * 8]);
                acc1[0][nt] = MFMA(a0, b, acc1[0][nt]);
                acc1[1][nt] = MFMA(a1, b, acc1[1][nt]);
            }
        }
        #pragma unroll
        for (int ks = 2; ks < 4; ks++) {
            half8 ap = (ks == 2) ? pa0 : pa1;
            #pragma unroll
            for (int nt = 0; nt < 4; nt++) {
                half8 b = ld8(&lds_w[(4 + ks * 4 + nt) * 512 + lane * 8]);
                acc1[0][nt] = MFMA(ap, b, acc1[0][nt]);
                acc1[1][nt] = MFMA(ap, b, acc1[1][nt]);
            }
        }
        // ReLU only (mask not needed between l1/l2), overwrite fg
        #pragma unroll
        for (int nt = 0; nt < 4; nt++)
            #pragma unroll
            for (int mt = 0; mt < 2; mt++)
                #pragma unroll
                for (int r = 0; r < 4; r++) {
                    float v = fmaxf(acc1[mt][nt][r], 0.f);
                    fg[wave][(mt * 16 + q * 4 + r) * 72 + nt * 16 + l15] = (half_t)v;
                }

        // ---- l2: (32x64) @ (64x64), acc init sC2 ----
        f32x4 acc2[2][4];
        #pragma unroll
        for (int mt = 0; mt < 2; mt++)
            #pragma unroll
            for (int nt = 0; nt < 4; nt++)
                #pragma unroll
                for (int r = 0; r < 4; r++) acc2[mt][nt][r] = sC2[nt];
        #pragma unroll
        for (int ks = 0; ks < 2; ks++) {
            half8 a0 = ld8(&fg[wave][l15 * 72 + ks * 32 + q * 8]);
            half8 a1 = ld8(&fg[wave][(l15 + 16) * 72 + ks * 32 + q * 8]);
            #pragma unroll
            for (int nt = 0; nt < 4; nt++) {
                half8 b = ld8(&lds_w[(20 + ks * 4 + nt) * 512 + lane * 8]);
                acc2[0][nt] = MFMA(a0, b, acc2[0][nt]);
                acc2[1][nt] = MFMA(a1, b, acc2[1][nt]);
            }
        }

        // ReLU+mask, masked max over points -> feat row into ft tile (f16)
        float fm[4];
        #pragma unroll
        for (int nt = 0; nt < 4; nt++) {
            float m = 0.f;
            #pragma unroll
            for (int mt = 0; mt < 2; mt++)
                #pragma unroll
                for (int r = 0; r < 4; r++) {
                    float v = fmaxf(acc2[mt][nt][r], 0.f) * maskf[mt * 4 + r];
                    m = fmaxf(m, v);
                }
            m = fmaxf(m, __shfl_xor(m, 16));
            m = fmaxf(m, __shfl_xor(m, 32));
            fm[nt] = m;
        }
        float fv = (q == 0) ? fm[0] : (q == 1) ? fm[1] : (q == 2) ? fm[2] : fm[3];
        ft[(wave * 4 + it) * 72 + lane] = (half_t)fv;   // row = 4w+it, col = lane

        int lm = 0;
        #pragma unroll
        for (int j = 0; j < 8; j++) lm |= (maskf[j] != 0.f);
        unsigned long long bal = __ballot(lm);
        if (lane == 0) validb[wave * 4 + it] = bal ? 1 : 0;

        // ---- commit prefetch for next iteration ----
        if (it < 3) {
            if (lane >= 32) maskb[wave][(it + 1) & 1][lane - 32] = mnext;
            #pragma unroll
            for (int mt = 0; mt < 2; mt++)
                #pragma unroll
                for (int j = 0; j < 8; j++) xr[mt][j] = xn[mt][j];
        }
    }

    // =============== out-MLP stage (M=32 rows per block) ===============
    // 8 waves <-> 8 tiles: wave w owns (mt_o = w>>2, nt1 = w&3) for out1,
    // and nt2 = nt1 + 4t (t=0,1) for out2. B-frags straight from global
    // (L2-resident); loads issued before the barrier to overlap arrival.
    const int mt_o = wave >> 2, nt1 = wave & 3;
    float bb1 = b1[nt1 * 16 + l15];
    half8 bw1[2];
    #pragma unroll
    for (int ks = 0; ks < 2; ks++)
        #pragma unroll
        for (int j = 0; j < 8; j++)
            bw1[ks][j] = (half_t)w1[(ks * 32 + q * 8 + j) * 64 + nt1 * 16 + l15];

    float bb2[2];
    half8 bw2[2][2];   // [ks][t]
    #pragma unroll
    for (int t = 0; t < 2; t++) {
        int c = (nt1 + 4 * t) * 16 + l15;
        bb2[t] = b2[c];
        #pragma unroll
        for (int ks = 0; ks < 2; ks++)
            #pragma unroll
            for (int j = 0; j < 8; j++)
                bw2[ks][t][j] = (half_t)w2[(ks * 32 + q * 8 + j) * 128 + c];
    }

    __syncthreads();   // ft + validb complete

    // out1: wave w computes rows mt_o*16.., cols nt1*16..
    f32x4 o1;
    #pragma unroll
    for (int r = 0; r < 4; r++) o1[r] = bb1;
    #pragma unroll
    for (int ks = 0; ks < 2; ks++) {
        half8 a = ld8(&ft[(mt_o * 16 + l15) * 72 + ks * 32 + q * 8]);
        o1 = MFMA(a, bw1[ks], o1);
    }
    #pragma unroll
    for (int r = 0; r < 4; r++) {
        float v = fmaxf(o1[r], 0.f);
        qt[(mt_o * 16 + q * 4 + r) * 72 + nt1 * 16 + l15] = (half_t)v;
    }

    __syncthreads();   // qt complete

    // out2: wave w computes rows mt_o*16.., cols (nt1)*16 and (nt1+4)*16
    f32x4 o2[2];
    #pragma unroll
    for (int t = 0; t < 2; t++)
        #pragma unroll
        for (int r = 0; r < 4; r++) o2[t][r] = bb2[t];
    #pragma unroll
    for (int ks = 0; ks < 2; ks++) {
        half8 a = ld8(&qt[(mt_o * 16 + l15) * 72 + ks * 32 + q * 8]);
        o2[0] = MFMA(a, bw2[ks][0], o2[0]);
        o2[1] = MFMA(a, bw2[ks][1], o2[1]);
    }
    #pragma unroll
    for (int r = 0; r < 4; r++) {
        int row = mt_o * 16 + q * 4 + r;
        float vr = validb[row] ? 1.f : 0.f;
        long rowg = (long)(blockIdx.x * 32 + row);
        out[rowg * 128 + (nt1 + 0) * 16 + l15] = o2[0][r] * vr;
        out[rowg * 128 + (nt1 + 4) * 16 + l15] = o2[1][r] * vr;
    }
}

extern "C" void kernel_launch(void* const* d_in, const int* in_sizes, int n_in,
                              void* d_out, int out_size, void* d_ws, size_t ws_size,
                              hipStream_t stream) {
    (void)in_sizes; (void)n_in; (void)out_size; (void)d_ws; (void)ws_size;
    k_fused<<<dim3(NPOLY / 32), dim3(512), 0, stream>>>(
        (const float*)d_in[0], (const int*)d_in[1],
        (const float*)d_in[2],  (const float*)d_in[3],  (const float*)d_in[4],
        (const float*)d_in[5],  (const float*)d_in[6],  (const float*)d_in[7],
        (const float*)d_in[8],  (const float*)d_in[9],  (const float*)d_in[10],
        (const float*)d_in[11], (const float*)d_in[12], (const float*)d_in[13],
        (const float*)d_in[14], (const float*)d_in[15], (const float*)d_in[16],
        (const float*)d_in[17], (const float*)d_in[18], (const float*)d_in[19],
        (const float*)d_in[20], (const float*)d_in[21],
        (const float*)d_in[22], (const float*)d_in[23],
        (float*)d_out);
}

// Round 3
// 146.532 us; speedup vs baseline: 1.3978x; 1.1994x over previous
//
#include <hip/hip_runtime.h>

typedef _Float16 half_t;
typedef __attribute__((ext_vector_type(8))) _Float16 half8;   // MFMA A/B frag (4 VGPRs)
typedef __attribute__((ext_vector_type(4))) float f32x4;      // MFMA C/D frag

#define NPOLY 16384   // B*N
#define PPTS  32
#define CIN   9

__device__ __forceinline__ half8 ld8(const half_t* p){
    return *reinterpret_cast<const half8*>(p);
}
__device__ __forceinline__ f32x4 MFMA(half8 a, half8 b, f32x4 c){
    return __builtin_amdgcn_mfma_f32_16x16x32_f16(a, b, c, 0, 0, 0);
}
// Fragment layouts (measured, learn_hip m89/m120; dtype-independent):
//   A[m][k]: m = lane&15 (+16*mt), k = (lane>>4)*8 + j (+32*ks)
//   B[k][n]: n = lane&15 (+16*nt), k = (lane>>4)*8 + j (+32*ks)
//   C/D[row][col]: col = lane&15 (+16*nt), row = (lane>>4)*4 + r (+16*mt)

// =====================================================================
// Fully fused: pre-MLP -> mask -> maxpool -> concat -> l1 -> l2 ->
// masked max -> out1(relu) -> out2 -> valid mask.
// NOTE (round-1 lesson): d_ws is re-poisoned (268 MB fill) every
// iteration by the harness; reading it costs ~100us of L3 drain. All
// weight staging therefore stays IN-KERNEL, amortized per block.
// NOTE (round-2 lesson): __launch_bounds__ second arg acts as
// blocks/CU here: (512,4) forced VGPR<=64 -> ~100 MB scratch spill
// traffic. (512,2) caps VGPR at 128 -> no spill.
// Block = 512 threads (8 waves) = 32 polylines; wave w owns rows 4w..4w+3.
// Grid = 512 = 2 blocks/CU exactly -> 16 waves/CU resident, single
// balanced round. LDS 76.5 KB -> 2 blocks/CU.
// =====================================================================
__global__ __launch_bounds__(512, 2) void k_fused(
    const float* __restrict__ px,        // [NPOLY][32][9]
    const int*   __restrict__ pmask,     // [NPOLY][32]
    const float* __restrict__ w_pre, const float* __restrict__ b_pre,
    const float* __restrict__ g_pre, const float* __restrict__ be_pre,
    const float* __restrict__ rm_pre, const float* __restrict__ rv_pre,
    const float* __restrict__ w_m1, const float* __restrict__ b_m1,
    const float* __restrict__ g_m1, const float* __restrict__ be_m1,
    const float* __restrict__ rm_m1, const float* __restrict__ rv_m1,
    const float* __restrict__ w_m2, const float* __restrict__ b_m2,
    const float* __restrict__ g_m2, const float* __restrict__ be_m2,
    const float* __restrict__ rm_m2, const float* __restrict__ rv_m2,
    const float* __restrict__ w1, const float* __restrict__ b1,
    const float* __restrict__ w2, const float* __restrict__ b2,
    float* __restrict__ out)
{
    // encoder weight frags (f16, BN-scaled): pre 0..3, m1 4..19, m2 20..27
    __shared__ __align__(16) half_t lds_w[28 * 512];   // 28 KB
    __shared__ __align__(16) half_t fg[8][32 * 72];    // 36 KB per-wave f/g A-tiles
    __shared__ __align__(16) half_t pooledb[8][64];    // 1 KB
    __shared__ __align__(16) half_t ft[32 * 72];       // 4.5 KB feat A-tile (32 rows)
    __shared__ __align__(16) half_t qt[32 * 72];       // 4.5 KB out1 A-tile
    __shared__ int maskb[8][2][32];                    // 2 KB (double-buffered)
    __shared__ int validb[32];

    const int tid  = threadIdx.x;
    const int wave = tid >> 6, lane = tid & 63, l15 = lane & 15, q = lane >> 4;

    // ---- stage encoder weights, fp32 -> f16, folding BN scale sA ----
    for (int s = tid; s < 28 * 64; s += 512) {
        int frag = s >> 6, ln = s & 63;
        const float *W, *G, *RV; int K, ks, nt;
        if (frag < 4)       { W = w_pre; G = g_pre; RV = rv_pre; K = CIN; ks = 0; nt = frag; }
        else if (frag < 20) { W = w_m1;  G = g_m1;  RV = rv_m1;  K = 128; int f = frag - 4;  ks = f >> 2; nt = f & 3; }
        else                { W = w_m2;  G = g_m2;  RV = rv_m2;  K = 64;  int f = frag - 20; ks = f >> 2; nt = f & 3; }
        int col = nt * 16 + (ln & 15);
        int kb  = ks * 32 + ((ln >> 4) << 3);
        float sA = G[col] * rsqrtf(RV[col] + 1e-5f);
        half_t* dst = &lds_w[s * 8];
        #pragma unroll
        for (int j = 0; j < 8; j++) {
            int k  = kb + j;
            int ka = (k < K) ? k : 0;
            float v = W[ka * 64 + col] * sA;
            dst[j] = (k < K) ? (half_t)v : (half_t)0.f;
        }
    }

    // ---- per-lane BN bias consts (go into MFMA acc init), h = nt*16+l15 ----
    float sC0[4], sC1[4], sC2[4];
    #pragma unroll
    for (int nt = 0; nt < 4; nt++) {
        int h = nt * 16 + l15; float a;
        a = g_pre[h] * rsqrtf(rv_pre[h] + 1e-5f); sC0[nt] = (b_pre[h] - rm_pre[h]) * a + be_pre[h];
        a = g_m1[h]  * rsqrtf(rv_m1[h]  + 1e-5f); sC1[nt] = (b_m1[h]  - rm_m1[h])  * a + be_m1[h];
        a = g_m2[h]  * rsqrtf(rv_m2[h]  + 1e-5f); sC2[nt] = (b_m2[h]  - rm_m2[h])  * a + be_m2[h];
    }

    const int nbase = blockIdx.x * 32 + wave * 4;

    // ---- prefetch iter 0 x (lanes q<2) and mask (lanes 32..63) ----
    float xr[2][8];
    #pragma unroll
    for (int mt = 0; mt < 2; mt++) {
        const float* src = px + ((long)nbase * PPTS + l15 + 16 * mt) * CIN;
        if (q == 0) {
            #pragma unroll
            for (int j = 0; j < 8; j++) xr[mt][j] = src[j];
        } else if (q == 1) {
            xr[mt][0] = src[8];
        }
    }
    if (lane >= 32) maskb[wave][0][lane - 32] = pmask[nbase * PPTS + (lane - 32)];

    __syncthreads();   // weights staged

    // pre-layer B-frags are reused every iteration: hoist to registers
    half8 preb[4];
    #pragma unroll
    for (int nt = 0; nt < 4; nt++) preb[nt] = ld8(&lds_w[nt * 512 + lane * 8]);

    #pragma unroll
    for (int it = 0; it < 4; ++it) {
        const int n = nbase + it;

        // ---- issue next-iteration prefetch loads (consumed at iter end) ----
        float xn[2][8]; int mnext = 0;
        if (it < 3) {
            #pragma unroll
            for (int mt = 0; mt < 2; mt++) {
                const float* src = px + ((long)(n + 1) * PPTS + l15 + 16 * mt) * CIN;
                if (q == 0) {
                    #pragma unroll
                    for (int j = 0; j < 8; j++) xn[mt][j] = src[j];
                } else if (q == 1) {
                    xn[mt][0] = src[8];
                }
            }
            if (lane >= 32) mnext = pmask[(n + 1) * PPTS + (lane - 32)];
        }

        // ---- build x A-frags (K=9 zero-padded to 32) ----
        half8 xa[2];
        #pragma unroll
        for (int mt = 0; mt < 2; mt++) {
            half8 v;
            #pragma unroll
            for (int j = 0; j < 8; j++) v[j] = (half_t)0.f;
            if (q == 0) {
                #pragma unroll
                for (int j = 0; j < 8; j++) v[j] = (half_t)xr[mt][j];
            } else if (q == 1) {
                v[0] = (half_t)xr[mt][0];
            }
            xa[mt] = v;
        }

        // ---- pre layer: acc init = sC0 (BN bias) ----
        f32x4 acc[2][4];
        #pragma unroll
        for (int mt = 0; mt < 2; mt++)
            #pragma unroll
            for (int nt = 0; nt < 4; nt++)
                #pragma unroll
                for (int r = 0; r < 4; r++) acc[mt][nt][r] = sC0[nt];

        #pragma unroll
        for (int nt = 0; nt < 4; nt++) {
            acc[0][nt] = MFMA(xa[0], preb[nt], acc[0][nt]);
            acc[1][nt] = MFMA(xa[1], preb[nt], acc[1][nt]);
        }

        float maskf[8];
        #pragma unroll
        for (int mt = 0; mt < 2; mt++)
            #pragma unroll
            for (int r = 0; r < 4; r++)
                maskf[mt * 4 + r] = maskb[wave][it & 1][mt * 16 + q * 4 + r] ? 1.f : 0.f;

        // ReLU+mask, write masked f into A-tile, track pooled max (vals >= 0)
        float pm[4];
        #pragma unroll
        for (int nt = 0; nt < 4; nt++) {
            float m = 0.f;
            #pragma unroll
            for (int mt = 0; mt < 2; mt++)
                #pragma unroll
                for (int r = 0; r < 4; r++) {
                    float v = fmaxf(acc[mt][nt][r], 0.f) * maskf[mt * 4 + r];
                    fg[wave][(mt * 16 + q * 4 + r) * 72 + nt * 16 + l15] = (half_t)v;
                    m = fmaxf(m, v);
                }
            m = fmaxf(m, __shfl_xor(m, 16));
            m = fmaxf(m, __shfl_xor(m, 32));
            pm[nt] = m;
        }
        {
            float pv = (q == 0) ? pm[0] : (q == 1) ? pm[1] : (q == 2) ? pm[2] : pm[3];
            pooledb[wave][lane] = (half_t)pv;   // col = q*16+l15 = lane
        }

        // ---- l1: A = [f | pooled-bcast] (32x128) @ (128x64), acc init sC1 ----
        f32x4 acc1[2][4];
        #pragma unroll
        for (int mt = 0; mt < 2; mt++)
            #pragma unroll
            for (int nt = 0; nt < 4; nt++)
                #pragma unroll
                for (int r = 0; r < 4; r++) acc1[mt][nt][r] = sC1[nt];

        half8 pa0 = ld8(&pooledb[wave][q * 8]);
        half8 pa1 = ld8(&pooledb[wave][32 + q * 8]);
        #pragma unroll
        for (int ks = 0; ks < 2; ks++) {
            half8 a0 = ld8(&fg[wave][l15 * 72 + ks * 32 + q * 8]);
            half8 a1 = ld8(&fg[wave][(l15 + 16) * 72 + ks * 32 + q * 8]);
            #pragma unroll
            for (int nt = 0; nt < 4; nt++) {
                half8 b = ld8(&lds_w[(4 + ks * 4 + nt) * 512 + lane * 8]);
                acc1[0][nt] = MFMA(a0, b, acc1[0][nt]);
                acc1[1][nt] = MFMA(a1, b, acc1[1][nt]);
            }
        }
        #pragma unroll
        for (int ks = 2; ks < 4; ks++) {
            half8 ap = (ks == 2) ? pa0 : pa1;
            #pragma unroll
            for (int nt = 0; nt < 4; nt++) {
                half8 b = ld8(&lds_w[(4 + ks * 4 + nt) * 512 + lane * 8]);
                acc1[0][nt] = MFMA(ap, b, acc1[0][nt]);
                acc1[1][nt] = MFMA(ap, b, acc1[1][nt]);
            }
        }
        // ReLU only (mask not needed between l1/l2), overwrite fg
        #pragma unroll
        for (int nt = 0; nt < 4; nt++)
            #pragma unroll
            for (int mt = 0; mt < 2; mt++)
                #pragma unroll
                for (int r = 0; r < 4; r++) {
                    float v = fmaxf(acc1[mt][nt][r], 0.f);
                    fg[wave][(mt * 16 + q * 4 + r) * 72 + nt * 16 + l15] = (half_t)v;
                }

        // ---- l2: (32x64) @ (64x64), acc init sC2 ----
        f32x4 acc2[2][4];
        #pragma unroll
        for (int mt = 0; mt < 2; mt++)
            #pragma unroll
            for (int nt = 0; nt < 4; nt++)
                #pragma unroll
                for (int r = 0; r < 4; r++) acc2[mt][nt][r] = sC2[nt];
        #pragma unroll
        for (int ks = 0; ks < 2; ks++) {
            half8 a0 = ld8(&fg[wave][l15 * 72 + ks * 32 + q * 8]);
            half8 a1 = ld8(&fg[wave][(l15 + 16) * 72 + ks * 32 + q * 8]);
            #pragma unroll
            for (int nt = 0; nt < 4; nt++) {
                half8 b = ld8(&lds_w[(20 + ks * 4 + nt) * 512 + lane * 8]);
                acc2[0][nt] = MFMA(a0, b, acc2[0][nt]);
                acc2[1][nt] = MFMA(a1, b, acc2[1][nt]);
            }
        }

        // ReLU+mask, masked max over points -> feat row into ft tile (f16)
        float fm[4];
        #pragma unroll
        for (int nt = 0; nt < 4; nt++) {
            float m = 0.f;
            #pragma unroll
            for (int mt = 0; mt < 2; mt++)
                #pragma unroll
                for (int r = 0; r < 4; r++) {
                    float v = fmaxf(acc2[mt][nt][r], 0.f) * maskf[mt * 4 + r];
                    m = fmaxf(m, v);
                }
            m = fmaxf(m, __shfl_xor(m, 16));
            m = fmaxf(m, __shfl_xor(m, 32));
            fm[nt] = m;
        }
        float fv = (q == 0) ? fm[0] : (q == 1) ? fm[1] : (q == 2) ? fm[2] : fm[3];
        ft[(wave * 4 + it) * 72 + lane] = (half_t)fv;   // row = 4w+it, col = lane

        int lm = 0;
        #pragma unroll
        for (int j = 0; j < 8; j++) lm |= (maskf[j] != 0.f);
        unsigned long long bal = __ballot(lm);
        if (lane == 0) validb[wave * 4 + it] = bal ? 1 : 0;

        // ---- commit prefetch for next iteration ----
        if (it < 3) {
            if (lane >= 32) maskb[wave][(it + 1) & 1][lane - 32] = mnext;
            #pragma unroll
            for (int mt = 0; mt < 2; mt++)
                #pragma unroll
                for (int j = 0; j < 8; j++) xr[mt][j] = xn[mt][j];
        }
    }

    // =============== out-MLP stage (M=32 rows per block) ===============
    // 8 waves <-> 8 tiles: wave w owns (mt_o = w>>2, nt1 = w&3) for out1,
    // and nt2 = nt1 + 4t (t=0,1) for out2. B-frags straight from global
    // (L2-resident); loads issued before the barrier to overlap arrival.
    const int mt_o = wave >> 2, nt1 = wave & 3;
    float bb1 = b1[nt1 * 16 + l15];
    half8 bw1[2];
    #pragma unroll
    for (int ks = 0; ks < 2; ks++)
        #pragma unroll
        for (int j = 0; j < 8; j++)
            bw1[ks][j] = (half_t)w1[(ks * 32 + q * 8 + j) * 64 + nt1 * 16 + l15];

    float bb2[2];
    half8 bw2[2][2];   // [ks][t]
    #pragma unroll
    for (int t = 0; t < 2; t++) {
        int c = (nt1 + 4 * t) * 16 + l15;
        bb2[t] = b2[c];
        #pragma unroll
        for (int ks = 0; ks < 2; ks++)
            #pragma unroll
            for (int j = 0; j < 8; j++)
                bw2[ks][t][j] = (half_t)w2[(ks * 32 + q * 8 + j) * 128 + c];
    }

    __syncthreads();   // ft + validb complete

    // out1: wave w computes rows mt_o*16.., cols nt1*16..
    f32x4 o1;
    #pragma unroll
    for (int r = 0; r < 4; r++) o1[r] = bb1;
    #pragma unroll
    for (int ks = 0; ks < 2; ks++) {
        half8 a = ld8(&ft[(mt_o * 16 + l15) * 72 + ks * 32 + q * 8]);
        o1 = MFMA(a, bw1[ks], o1);
    }
    #pragma unroll
    for (int r = 0; r < 4; r++) {
        float v = fmaxf(o1[r], 0.f);
        qt[(mt_o * 16 + q * 4 + r) * 72 + nt1 * 16 + l15] = (half_t)v;
    }

    __syncthreads();   // qt complete

    // out2: wave w computes rows mt_o*16.., cols (nt1)*16 and (nt1+4)*16
    f32x4 o2[2];
    #pragma unroll
    for (int t = 0; t < 2; t++)
        #pragma unroll
        for (int r = 0; r < 4; r++) o2[t][r] = bb2[t];
    #pragma unroll
    for (int ks = 0; ks < 2; ks++) {
        half8 a = ld8(&qt[(mt_o * 16 + l15) * 72 + ks * 32 + q * 8]);
        o2[0] = MFMA(a, bw2[ks][0], o2[0]);
        o2[1] = MFMA(a, bw2[ks][1], o2[1]);
    }
    #pragma unroll
    for (int r = 0; r < 4; r++) {
        int row = mt_o * 16 + q * 4 + r;
        float vr = validb[row] ? 1.f : 0.f;
        long rowg = (long)(blockIdx.x * 32 + row);
        out[rowg * 128 + (nt1 + 0) * 16 + l15] = o2[0][r] * vr;
        out[rowg * 128 + (nt1 + 4) * 16 + l15] = o2[1][r] * vr;
    }
}

extern "C" void kernel_launch(void* const* d_in, const int* in_sizes, int n_in,
                              void* d_out, int out_size, void* d_ws, size_t ws_size,
                              hipStream_t stream) {
    (void)in_sizes; (void)n_in; (void)out_size; (void)d_ws; (void)ws_size;
    k_fused<<<dim3(NPOLY / 32), dim3(512), 0, stream>>>(
        (const float*)d_in[0], (const int*)d_in[1],
        (const float*)d_in[2],  (const float*)d_in[3],  (const float*)d_in[4],
        (const float*)d_in[5],  (const float*)d_in[6],  (const float*)d_in[7],
        (const float*)d_in[8],  (const float*)d_in[9],  (const float*)d_in[10],
        (const float*)d_in[11], (const float*)d_in[12], (const float*)d_in[13],
        (const float*)d_in[14], (const float*)d_in[15], (const float*)d_in[16],
        (const float*)d_in[17], (const float*)d_in[18], (const float*)d_in[19],
        (const float*)d_in[20], (const float*)d_in[21],
        (const float*)d_in[22], (const float*)d_in[23],
        (float*)d_out);
}

// Round 4
// 143.169 us; speedup vs baseline: 1.4306x; 1.0235x over previous
//
#include <hip/hip_runtime.h>

typedef _Float16 half_t;
typedef __attribute__((ext_vector_type(8))) _Float16 half8;   // MFMA A/B frag (4 VGPRs)
typedef __attribute__((ext_vector_type(4))) float f32x4;      // MFMA C/D frag

#define NPOLY 16384   // B*N
#define PPTS  32
#define CIN   9

__device__ __forceinline__ half8 ld8(const half_t* p){
    return *reinterpret_cast<const half8*>(p);
}
__device__ __forceinline__ f32x4 MFMA(half8 a, half8 b, f32x4 c){
    return __builtin_amdgcn_mfma_f32_16x16x32_f16(a, b, c, 0, 0, 0);
}
// Fragment layouts (measured, learn_hip m89/m120; dtype-independent):
//   A[m][k]: m = lane&15 (+16*mt), k = (lane>>4)*8 + j (+32*ks)
//   B[k][n]: n = lane&15 (+16*nt), k = (lane>>4)*8 + j (+32*ks)
//   C/D[row][col]: col = lane&15 (+16*nt), row = (lane>>4)*4 + r (+16*mt)

// =====================================================================
// Fully fused: pre-MLP -> mask -> maxpool -> concat -> l1 -> l2 ->
// masked max -> out1(relu) -> out2 -> valid mask.
// NOTE (round-1 lesson): d_ws is re-poisoned (268 MB fill) every
// iteration by the harness; reading it costs ~100us of L3 drain. All
// weight staging therefore stays IN-KERNEL, amortized per block.
// NOTE (round-2 lesson): __launch_bounds__ second arg acts as
// blocks/CU here: (512,4) forced VGPR<=64 -> ~100 MB scratch spill
// traffic. (512,2) caps VGPR at 128 -> no spill (VGPR=88).
// NOTE (round-3 lesson): occupancy 12->16 waves/CU did NOT move dur
// (45.5 vs 46.7us); VALUBusy pinned ~40% in both. Theory: the 4x
// unrolled it-loop is ~30-35KB of code -> I-cache (32KB/CU) thrash,
// shared by all waves -> issue-rate cap insensitive to wave count.
// THIS ROUND: roll the it-loop (body ~7KB, I-cache-resident).
// Block = 512 threads (8 waves) = 32 polylines; wave w owns rows 4w..4w+3.
// Grid = 512 = 2 blocks/CU exactly. LDS 76.5 KB -> 2 blocks/CU.
// =====================================================================
__global__ __launch_bounds__(512, 2) void k_fused(
    const float* __restrict__ px,        // [NPOLY][32][9]
    const int*   __restrict__ pmask,     // [NPOLY][32]
    const float* __restrict__ w_pre, const float* __restrict__ b_pre,
    const float* __restrict__ g_pre, const float* __restrict__ be_pre,
    const float* __restrict__ rm_pre, const float* __restrict__ rv_pre,
    const float* __restrict__ w_m1, const float* __restrict__ b_m1,
    const float* __restrict__ g_m1, const float* __restrict__ be_m1,
    const float* __restrict__ rm_m1, const float* __restrict__ rv_m1,
    const float* __restrict__ w_m2, const float* __restrict__ b_m2,
    const float* __restrict__ g_m2, const float* __restrict__ be_m2,
    const float* __restrict__ rm_m2, const float* __restrict__ rv_m2,
    const float* __restrict__ w1, const float* __restrict__ b1,
    const float* __restrict__ w2, const float* __restrict__ b2,
    float* __restrict__ out)
{
    // encoder weight frags (f16, BN-scaled): pre 0..3, m1 4..19, m2 20..27
    __shared__ __align__(16) half_t lds_w[28 * 512];   // 28 KB
    __shared__ __align__(16) half_t fg[8][32 * 72];    // 36 KB per-wave f/g A-tiles
    __shared__ __align__(16) half_t pooledb[8][64];    // 1 KB
    __shared__ __align__(16) half_t ft[32 * 72];       // 4.5 KB feat A-tile (32 rows)
    __shared__ __align__(16) half_t qt[32 * 72];       // 4.5 KB out1 A-tile
    __shared__ int maskb[8][2][32];                    // 2 KB (double-buffered)
    __shared__ int validb[32];

    const int tid  = threadIdx.x;
    const int wave = tid >> 6, lane = tid & 63, l15 = lane & 15, q = lane >> 4;

    // ---- stage encoder weights, fp32 -> f16, folding BN scale sA ----
    #pragma unroll 1
    for (int s = tid; s < 28 * 64; s += 512) {
        int frag = s >> 6, ln = s & 63;
        const float *W, *G, *RV; int K, ks, nt;
        if (frag < 4)       { W = w_pre; G = g_pre; RV = rv_pre; K = CIN; ks = 0; nt = frag; }
        else if (frag < 20) { W = w_m1;  G = g_m1;  RV = rv_m1;  K = 128; int f = frag - 4;  ks = f >> 2; nt = f & 3; }
        else                { W = w_m2;  G = g_m2;  RV = rv_m2;  K = 64;  int f = frag - 20; ks = f >> 2; nt = f & 3; }
        int col = nt * 16 + (ln & 15);
        int kb  = ks * 32 + ((ln >> 4) << 3);
        float sA = G[col] * rsqrtf(RV[col] + 1e-5f);
        half_t* dst = &lds_w[s * 8];
        #pragma unroll
        for (int j = 0; j < 8; j++) {
            int k  = kb + j;
            int ka = (k < K) ? k : 0;
            float v = W[ka * 64 + col] * sA;
            dst[j] = (k < K) ? (half_t)v : (half_t)0.f;
        }
    }

    // ---- per-lane BN bias consts (go into MFMA acc init), h = nt*16+l15 ----
    float sC0[4], sC1[4], sC2[4];
    #pragma unroll
    for (int nt = 0; nt < 4; nt++) {
        int h = nt * 16 + l15; float a;
        a = g_pre[h] * rsqrtf(rv_pre[h] + 1e-5f); sC0[nt] = (b_pre[h] - rm_pre[h]) * a + be_pre[h];
        a = g_m1[h]  * rsqrtf(rv_m1[h]  + 1e-5f); sC1[nt] = (b_m1[h]  - rm_m1[h])  * a + be_m1[h];
        a = g_m2[h]  * rsqrtf(rv_m2[h]  + 1e-5f); sC2[nt] = (b_m2[h]  - rm_m2[h])  * a + be_m2[h];
    }

    const int nbase = blockIdx.x * 32 + wave * 4;

    // ---- prefetch iter 0 x (lanes q<2) and mask (lanes 32..63) ----
    float xr[2][8];
    #pragma unroll
    for (int mt = 0; mt < 2; mt++) {
        const float* src = px + ((long)nbase * PPTS + l15 + 16 * mt) * CIN;
        if (q == 0) {
            #pragma unroll
            for (int j = 0; j < 8; j++) xr[mt][j] = src[j];
        } else if (q == 1) {
            xr[mt][0] = src[8];
        }
    }
    if (lane >= 32) maskb[wave][0][lane - 32] = pmask[nbase * PPTS + (lane - 32)];

    __syncthreads();   // weights staged

    // pre-layer B-frags are reused every iteration: hoist to registers
    half8 preb[4];
    #pragma unroll
    for (int nt = 0; nt < 4; nt++) preb[nt] = ld8(&lds_w[nt * 512 + lane * 8]);

    // ---- main loop: ROLLED (code size ~7KB, I-cache resident) ----
    #pragma unroll 1
    for (int it = 0; it < 4; ++it) {
        const int n = nbase + it;

        // ---- issue next-iteration prefetch loads (consumed at iter end) ----
        float xn[2][8]; int mnext = 0;
        if (it < 3) {
            #pragma unroll
            for (int mt = 0; mt < 2; mt++) {
                const float* src = px + ((long)(n + 1) * PPTS + l15 + 16 * mt) * CIN;
                if (q == 0) {
                    #pragma unroll
                    for (int j = 0; j < 8; j++) xn[mt][j] = src[j];
                } else if (q == 1) {
                    xn[mt][0] = src[8];
                }
            }
            if (lane >= 32) mnext = pmask[(n + 1) * PPTS + (lane - 32)];
        }

        // ---- build x A-frags (K=9 zero-padded to 32) ----
        half8 xa[2];
        #pragma unroll
        for (int mt = 0; mt < 2; mt++) {
            half8 v;
            #pragma unroll
            for (int j = 0; j < 8; j++) v[j] = (half_t)0.f;
            if (q == 0) {
                #pragma unroll
                for (int j = 0; j < 8; j++) v[j] = (half_t)xr[mt][j];
            } else if (q == 1) {
                v[0] = (half_t)xr[mt][0];
            }
            xa[mt] = v;
        }

        // ---- pre layer: acc init = sC0 (BN bias) ----
        f32x4 acc[2][4];
        #pragma unroll
        for (int mt = 0; mt < 2; mt++)
            #pragma unroll
            for (int nt = 0; nt < 4; nt++)
                #pragma unroll
                for (int r = 0; r < 4; r++) acc[mt][nt][r] = sC0[nt];

        #pragma unroll
        for (int nt = 0; nt < 4; nt++) {
            acc[0][nt] = MFMA(xa[0], preb[nt], acc[0][nt]);
            acc[1][nt] = MFMA(xa[1], preb[nt], acc[1][nt]);
        }

        float maskf[8];
        #pragma unroll
        for (int mt = 0; mt < 2; mt++)
            #pragma unroll
            for (int r = 0; r < 4; r++)
                maskf[mt * 4 + r] = maskb[wave][it & 1][mt * 16 + q * 4 + r] ? 1.f : 0.f;

        // ReLU+mask, write masked f into A-tile, track pooled max (vals >= 0)
        float pm[4];
        #pragma unroll
        for (int nt = 0; nt < 4; nt++) {
            float m = 0.f;
            #pragma unroll
            for (int mt = 0; mt < 2; mt++)
                #pragma unroll
                for (int r = 0; r < 4; r++) {
                    float v = fmaxf(acc[mt][nt][r], 0.f) * maskf[mt * 4 + r];
                    fg[wave][(mt * 16 + q * 4 + r) * 72 + nt * 16 + l15] = (half_t)v;
                    m = fmaxf(m, v);
                }
            m = fmaxf(m, __shfl_xor(m, 16));
            m = fmaxf(m, __shfl_xor(m, 32));
            pm[nt] = m;
        }
        {
            float pv = (q == 0) ? pm[0] : (q == 1) ? pm[1] : (q == 2) ? pm[2] : pm[3];
            pooledb[wave][lane] = (half_t)pv;   // col = q*16+l15 = lane
        }

        // ---- l1: A = [f | pooled-bcast] (32x128) @ (128x64), acc init sC1 ----
        f32x4 acc1[2][4];
        #pragma unroll
        for (int mt = 0; mt < 2; mt++)
            #pragma unroll
            for (int nt = 0; nt < 4; nt++)
                #pragma unroll
                for (int r = 0; r < 4; r++) acc1[mt][nt][r] = sC1[nt];

        half8 pa0 = ld8(&pooledb[wave][q * 8]);
        half8 pa1 = ld8(&pooledb[wave][32 + q * 8]);
        #pragma unroll
        for (int ks = 0; ks < 2; ks++) {
            half8 a0 = ld8(&fg[wave][l15 * 72 + ks * 32 + q * 8]);
            half8 a1 = ld8(&fg[wave][(l15 + 16) * 72 + ks * 32 + q * 8]);
            #pragma unroll
            for (int nt = 0; nt < 4; nt++) {
                half8 b = ld8(&lds_w[(4 + ks * 4 + nt) * 512 + lane * 8]);
                acc1[0][nt] = MFMA(a0, b, acc1[0][nt]);
                acc1[1][nt] = MFMA(a1, b, acc1[1][nt]);
            }
        }
        #pragma unroll
        for (int ks = 2; ks < 4; ks++) {
            half8 ap = (ks == 2) ? pa0 : pa1;
            #pragma unroll
            for (int nt = 0; nt < 4; nt++) {
                half8 b = ld8(&lds_w[(4 + ks * 4 + nt) * 512 + lane * 8]);
                acc1[0][nt] = MFMA(ap, b, acc1[0][nt]);
                acc1[1][nt] = MFMA(ap, b, acc1[1][nt]);
            }
        }
        // ReLU only (mask not needed between l1/l2), overwrite fg
        #pragma unroll
        for (int nt = 0; nt < 4; nt++)
            #pragma unroll
            for (int mt = 0; mt < 2; mt++)
                #pragma unroll
                for (int r = 0; r < 4; r++) {
                    float v = fmaxf(acc1[mt][nt][r], 0.f);
                    fg[wave][(mt * 16 + q * 4 + r) * 72 + nt * 16 + l15] = (half_t)v;
                }

        // ---- l2: (32x64) @ (64x64), acc init sC2 ----
        f32x4 acc2[2][4];
        #pragma unroll
        for (int mt = 0; mt < 2; mt++)
            #pragma unroll
            for (int nt = 0; nt < 4; nt++)
                #pragma unroll
                for (int r = 0; r < 4; r++) acc2[mt][nt][r] = sC2[nt];
        #pragma unroll
        for (int ks = 0; ks < 2; ks++) {
            half8 a0 = ld8(&fg[wave][l15 * 72 + ks * 32 + q * 8]);
            half8 a1 = ld8(&fg[wave][(l15 + 16) * 72 + ks * 32 + q * 8]);
            #pragma unroll
            for (int nt = 0; nt < 4; nt++) {
                half8 b = ld8(&lds_w[(20 + ks * 4 + nt) * 512 + lane * 8]);
                acc2[0][nt] = MFMA(a0, b, acc2[0][nt]);
                acc2[1][nt] = MFMA(a1, b, acc2[1][nt]);
            }
        }

        // ReLU+mask, masked max over points -> feat row into ft tile (f16)
        float fm[4];
        #pragma unroll
        for (int nt = 0; nt < 4; nt++) {
            float m = 0.f;
            #pragma unroll
            for (int mt = 0; mt < 2; mt++)
                #pragma unroll
                for (int r = 0; r < 4; r++) {
                    float v = fmaxf(acc2[mt][nt][r], 0.f) * maskf[mt * 4 + r];
                    m = fmaxf(m, v);
                }
            m = fmaxf(m, __shfl_xor(m, 16));
            m = fmaxf(m, __shfl_xor(m, 32));
            fm[nt] = m;
        }
        float fv = (q == 0) ? fm[0] : (q == 1) ? fm[1] : (q == 2) ? fm[2] : fm[3];
        ft[(wave * 4 + it) * 72 + lane] = (half_t)fv;   // row = 4w+it, col = lane

        int lm = 0;
        #pragma unroll
        for (int j = 0; j < 8; j++) lm |= (maskf[j] != 0.f);
        unsigned long long bal = __ballot(lm);
        if (lane == 0) validb[wave * 4 + it] = bal ? 1 : 0;

        // ---- commit prefetch for next iteration ----
        if (it < 3) {
            if (lane >= 32) maskb[wave][(it + 1) & 1][lane - 32] = mnext;
            #pragma unroll
            for (int mt = 0; mt < 2; mt++)
                #pragma unroll
                for (int j = 0; j < 8; j++) xr[mt][j] = xn[mt][j];
        }
    }

    // =============== out-MLP stage (M=32 rows per block) ===============
    // 8 waves <-> 8 tiles: wave w owns (mt_o = w>>2, nt1 = w&3) for out1,
    // and nt2 = nt1 + 4t (t=0,1) for out2. B-frags straight from global
    // (L2-resident); loads issued before the barrier to overlap arrival.
    const int mt_o = wave >> 2, nt1 = wave & 3;
    float bb1 = b1[nt1 * 16 + l15];
    half8 bw1[2];
    #pragma unroll
    for (int ks = 0; ks < 2; ks++)
        #pragma unroll
        for (int j = 0; j < 8; j++)
            bw1[ks][j] = (half_t)w1[(ks * 32 + q * 8 + j) * 64 + nt1 * 16 + l15];

    float bb2[2];
    half8 bw2[2][2];   // [ks][t]
    #pragma unroll
    for (int t = 0; t < 2; t++) {
        int c = (nt1 + 4 * t) * 16 + l15;
        bb2[t] = b2[c];
        #pragma unroll
        for (int ks = 0; ks < 2; ks++)
            #pragma unroll
            for (int j = 0; j < 8; j++)
                bw2[ks][t][j] = (half_t)w2[(ks * 32 + q * 8 + j) * 128 + c];
    }

    __syncthreads();   // ft + validb complete

    // out1: wave w computes rows mt_o*16.., cols nt1*16..
    f32x4 o1;
    #pragma unroll
    for (int r = 0; r < 4; r++) o1[r] = bb1;
    #pragma unroll
    for (int ks = 0; ks < 2; ks++) {
        half8 a = ld8(&ft[(mt_o * 16 + l15) * 72 + ks * 32 + q * 8]);
        o1 = MFMA(a, bw1[ks], o1);
    }
    #pragma unroll
    for (int r = 0; r < 4; r++) {
        float v = fmaxf(o1[r], 0.f);
        qt[(mt_o * 16 + q * 4 + r) * 72 + nt1 * 16 + l15] = (half_t)v;
    }

    __syncthreads();   // qt complete

    // out2: wave w computes rows mt_o*16.., cols (nt1)*16 and (nt1+4)*16
    f32x4 o2[2];
    #pragma unroll
    for (int t = 0; t < 2; t++)
        #pragma unroll
        for (int r = 0; r < 4; r++) o2[t][r] = bb2[t];
    #pragma unroll
    for (int ks = 0; ks < 2; ks++) {
        half8 a = ld8(&qt[(mt_o * 16 + l15) * 72 + ks * 32 + q * 8]);
        o2[0] = MFMA(a, bw2[ks][0], o2[0]);
        o2[1] = MFMA(a, bw2[ks][1], o2[1]);
    }
    #pragma unroll
    for (int r = 0; r < 4; r++) {
        int row = mt_o * 16 + q * 4 + r;
        float vr = validb[row] ? 1.f : 0.f;
        long rowg = (long)(blockIdx.x * 32 + row);
        out[rowg * 128 + (nt1 + 0) * 16 + l15] = o2[0][r] * vr;
        out[rowg * 128 + (nt1 + 4) * 16 + l15] = o2[1][r] * vr;
    }
}

extern "C" void kernel_launch(void* const* d_in, const int* in_sizes, int n_in,
                              void* d_out, int out_size, void* d_ws, size_t ws_size,
                              hipStream_t stream) {
    (void)in_sizes; (void)n_in; (void)out_size; (void)d_ws; (void)ws_size;
    k_fused<<<dim3(NPOLY / 32), dim3(512), 0, stream>>>(
        (const float*)d_in[0], (const int*)d_in[1],
        (const float*)d_in[2],  (const float*)d_in[3],  (const float*)d_in[4],
        (const float*)d_in[5],  (const float*)d_in[6],  (const float*)d_in[7],
        (const float*)d_in[8],  (const float*)d_in[9],  (const float*)d_in[10],
        (const float*)d_in[11], (const float*)d_in[12], (const float*)d_in[13],
        (const float*)d_in[14], (const float*)d_in[15], (const float*)d_in[16],
        (const float*)d_in[17], (const float*)d_in[18], (const float*)d_in[19],
        (const float*)d_in[20], (const float*)d_in[21],
        (const float*)d_in[22], (const float*)d_in[23],
        (float*)d_out);
}